// Round 4
// baseline (412.113 us; speedup 1.0000x reference)
//
#include <hip/hip_runtime.h>

#define N_PTS 32768
#define M_Q   8192
#define C_F   256
#define PS    8                 // point-range splits
#define SPTS  (N_PTS / PS)      // 4096 points per split
#define QG    (M_Q / 64)        // 128 query groups (64 queries = 1 wave) per side

__device__ __forceinline__ float rn_mul(float a, float b) { return __fmul_rn(a, b); }
__device__ __forceinline__ float rn_add(float a, float b) { return __fadd_rn(a, b); }

// Pack [x,y,z,b2] per point for both sides into workspace.
__global__ __launch_bounds__(256) void pack_pts(const float* __restrict__ c0,
                                                const float* __restrict__ c1,
                                                float4* __restrict__ pts) {
    int t = blockIdx.x * blockDim.x + threadIdx.x;   // 0 .. 2N-1
    int side = t >> 15;
    int n = t & (N_PTS - 1);
    const float* c = side ? c1 : c0;
    float x = c[n * 3 + 0], y = c[n * 3 + 1], z = c[n * 3 + 2];
    // numpy: sum(b*b, -1) = (x*x + y*y) + z*z, each op rounded, no fma
    float b2 = rn_add(rn_add(rn_mul(x, x), rn_mul(y, y)), rn_mul(z, z));
    pts[t] = make_float4(x, y, z, b2);
}

// One wave per block; lane = query. Stream SPTS wave-uniform points; per-lane
// exact top-2 with a ballot-gated update (fires ~14% of points).
__global__ __launch_bounds__(64) void pool_scan(
    const float* __restrict__ sc0, const float* __restrict__ sc1,
    const float4* __restrict__ pts, int4* __restrict__ part)
{
    int bid  = blockIdx.x;            // 2 * QG * PS = 2048
    int side = bid >> 10;
    int r    = bid & 1023;
    int qg   = r >> 3;                // 0..127
    int sp   = r & (PS - 1);          // 0..7
    int lane = threadIdx.x;           // 0..63 = query lane
    int q    = qg * 64 + lane;
    const float* sc = side ? sc1 : sc0;

    float ax = sc[q * 3 + 0], ay = sc[q * 3 + 1], az = sc[q * 3 + 2];
    float a2 = rn_add(rn_add(rn_mul(ax, ax), rn_mul(ay, ay)), rn_mul(az, az));

    float d1 = __int_as_float(0x7f800000), d2 = d1;   // +inf
    int   i1 = 0x7fffffff, i2 = 0x7fffffff;

    const float4* P = pts + (size_t)side * N_PTS + sp * SPTS;  // wave-uniform
    int base = sp * SPTS;

#pragma unroll 8
    for (int n = 0; n < SPTS; ++n) {
        float4 p = P[n];                               // uniform -> scalar load
        float dot = __builtin_fmaf(az, p.z,
                     __builtin_fmaf(ay, p.y, rn_mul(ax, p.x)));
        float d = __builtin_fmaf(-2.0f, dot, rn_add(a2, p.w));
        unsigned long long any = __ballot(d < d2);
        if (any) {                                     // uniform branch
            int pi = base + n;                         // scalar
            bool lt2 = d < d2;
            bool lt1 = d < d1;
            float nd2 = lt1 ? d1 : (lt2 ? d : d2);
            int   ni2 = lt1 ? i1 : (lt2 ? pi : i2);
            d1 = lt1 ? d : d1;
            i1 = lt1 ? pi : i1;
            d2 = nd2; i2 = ni2;
        }
    }

    // coalesced per-lane partial write
    part[((size_t)(side * QG + qg) * PS + sp) * 64 + lane] =
        make_int4(__float_as_int(d1), i1, __float_as_int(d2), i2);
}

// Merge the PS partials per query (exact lexicographic), gather feature rows.
__global__ __launch_bounds__(256) void merge_gather(
    const float* __restrict__ src, const float* __restrict__ tgt,
    const int4* __restrict__ part, float* __restrict__ out)
{
    __shared__ int sidx[8];

    int bid  = blockIdx.x;            // 2 * M_Q/8 = 2048
    int side = bid >> 10;
    int qb   = bid & 1023;
    const float* feats = side ? tgt : src;
    int tid = threadIdx.x;
    int q0  = qb * 8;

    if (tid < 8) {
        int q = q0 + tid;             // 0..8191
        int qg = q >> 6, lane = q & 63;
        const int4* pp = part + (size_t)(side * QG + qg) * PS * 64 + lane;
        int4 p0 = pp[0];
        float b1 = __int_as_float(p0.x), b2 = __int_as_float(p0.z);
        int   j1 = p0.y,                 j2 = p0.w;
#pragma unroll
        for (int sp = 1; sp < PS; ++sp) {
            int4 p = pp[sp * 64];
#pragma unroll
            for (int s = 0; s < 2; ++s) {
                float d = __int_as_float(s ? p.z : p.x);
                int   i = s ? p.w : p.y;
                bool lt1 = (d < b1) || (d == b1 && i < j1);
                bool lt2 = (d < b2) || (d == b2 && i < j2);
                b2 = lt1 ? b1 : (lt2 ? d : b2);
                j2 = lt1 ? j1 : (lt2 ? i : j2);
                b1 = lt1 ? d : b1;
                j1 = lt1 ? i : j1;
            }
        }
        sidx[tid] = j2;
    }
    __syncthreads();

    // gather: 8 rows of 256 floats; 32 threads per row, 2 float4 each
    int qi = tid >> 5;
    int cj = tid & 31;
    int row = sidx[qi];
    const float4* sp = (const float4*)(feats + (size_t)row * C_F);
    float4* dp = (float4*)(out + ((size_t)side * M_Q + q0 + qi) * (size_t)C_F);
    dp[cj]      = sp[cj];
    dp[cj + 32] = sp[cj + 32];
}

extern "C" void kernel_launch(void* const* d_in, const int* in_sizes, int n_in,
                              void* d_out, int out_size, void* d_ws, size_t ws_size,
                              hipStream_t stream) {
    const float* src  = (const float*)d_in[0];
    const float* tgt  = (const float*)d_in[1];
    const float* c0   = (const float*)d_in[2];  // src_coords   (N,3)
    const float* c1   = (const float*)d_in[3];  // tgt_coords   (N,3)
    const float* sh0  = (const float*)d_in[4];  // src_shortcut (M,3)
    const float* sh1  = (const float*)d_in[5];  // tgt_shortcut (M,3)
    float* out = (float*)d_out;

    float4* pts  = (float4*)d_ws;                               // 1 MB
    int4*   part = (int4*)((char*)d_ws + (size_t)2 * N_PTS * sizeof(float4)); // 2 MB

    hipLaunchKernelGGL(pack_pts, dim3(2 * N_PTS / 256), dim3(256), 0, stream,
                       c0, c1, pts);
    hipLaunchKernelGGL(pool_scan, dim3(2 * QG * PS), dim3(64), 0, stream,
                       sh0, sh1, pts, part);
    hipLaunchKernelGGL(merge_gather, dim3(2 * (M_Q / 8)), dim3(256), 0, stream,
                       src, tgt, part, out);
}

// Round 5
// 266.021 us; speedup vs baseline: 1.5492x; 1.5492x over previous
//
#include <hip/hip_runtime.h>

#define N_PTS 32768
#define M_Q   8192
#define C_F   256
#define QB    8              // queries per block
#define NW    4              // waves per block
#define SEED  2048           // seed points (phase A, full update)
#define SEEDW (SEED / NW)    // 512 per wave
#define NITA  (SEEDW / 64)   // 8 iterations
#define RESTN (N_PTS - SEED) // 30720
#define RESTW (RESTN / NW)   // 7680 per wave
#define NITB  (RESTW / 64)   // 120 iterations
#define NQB   (M_Q / QB)     // 1024 query blocks per side

__device__ __forceinline__ float rn_mul(float a, float b) { return __fmul_rn(a, b); }
__device__ __forceinline__ float rn_add(float a, float b) { return __fadd_rn(a, b); }

// exact-numpy distance: d = round((a2+b2) - 2*dot), dot = fma chain
__device__ __forceinline__ float qdist(float ax, float ay, float az, float a2,
                                       const float4& p) {
    float dot = __builtin_fmaf(az, p.z, __builtin_fmaf(ay, p.y, rn_mul(ax, p.x)));
    return __builtin_fmaf(-2.0f, dot, rn_add(a2, p.w));
}

// strict-< running top-2 (ascending-index stream => lowest-index-first on ties)
__device__ __forceinline__ void upd2(float d, int pi, float& d1, int& i1,
                                     float& d2, int& i2) {
    bool lt1 = d < d1, lt2 = d < d2;
    d2 = lt1 ? d1 : (lt2 ? d : d2);
    i2 = lt1 ? i1 : (lt2 ? pi : i2);
    d1 = lt1 ? d : d1;
    i1 = lt1 ? pi : i1;
}

// exact lexicographic (d,i) insert into running pair
__device__ __forceinline__ void ins_lex(float d, int i, float& b1, int& j1,
                                        float& b2, int& j2) {
    bool lt1 = (d < b1) || (d == b1 && i < j1);
    bool lt2 = (d < b2) || (d == b2 && i < j2);
    b2 = lt1 ? b1 : (lt2 ? d : b2);
    j2 = lt1 ? j1 : (lt2 ? i : j2);
    b1 = lt1 ? d : b1;
    j1 = lt1 ? i : j1;
}

// Pack [x,y,z,b2] per point for both sides into workspace.
__global__ __launch_bounds__(256) void pack_pts(const float* __restrict__ c0,
                                                const float* __restrict__ c1,
                                                float4* __restrict__ pts) {
    int t = blockIdx.x * blockDim.x + threadIdx.x;   // 0 .. 2N-1
    int side = t >> 15;
    int n = t & (N_PTS - 1);
    const float* c = side ? c1 : c0;
    float x = c[n * 3 + 0], y = c[n * 3 + 1], z = c[n * 3 + 2];
    float b2 = rn_add(rn_add(rn_mul(x, x), rn_mul(y, y)), rn_mul(z, z));
    pts[t] = make_float4(x, y, z, b2);
}

__global__ __launch_bounds__(256, 8) void pool_gather2(
    const float* __restrict__ src, const float* __restrict__ tgt,
    const float* __restrict__ sc0, const float* __restrict__ sc1,
    const float4* __restrict__ pts, float* __restrict__ out)
{
    __shared__ int4 wpart[NW][QB];   // per-wave partials (phase A, then B)
    __shared__ int4 seedm[QB];       // merged seed top-2 per query
    __shared__ int  sidx[QB];

    int bid  = blockIdx.x;           // 2 * NQB = 2048
    int side = bid >> 10;
    int qb   = bid & 1023;
    const float* feats = side ? tgt : src;
    const float* sc    = side ? sc1 : sc0;
    const float4* P    = pts + (size_t)side * N_PTS;

    int tid  = threadIdx.x;
    int wave = tid >> 6;
    int lane = tid & 63;
    int q0   = qb * QB;

    float ax[QB], ay[QB], az[QB], a2[QB];
    float d1[QB], d2[QB];
    int   i1[QB], i2[QB];
#pragma unroll
    for (int qi = 0; qi < QB; ++qi) {
        int q = q0 + qi;
        float x = sc[q * 3 + 0], y = sc[q * 3 + 1], z = sc[q * 3 + 2];
        ax[qi] = x; ay[qi] = y; az[qi] = z;
        a2[qi] = rn_add(rn_add(rn_mul(x, x), rn_mul(y, y)), rn_mul(z, z));
        d1[qi] = __int_as_float(0x7f800000); d2[qi] = d1[qi];
        i1[qi] = 0x7fffffff; i2[qi] = 0x7fffffff;
    }

    // ---------------- Phase A: exact top-2 over [0, SEED) ----------------
    {
        int basA = wave * SEEDW;
#pragma unroll 4
        for (int it = 0; it < NITA; ++it) {
            float4 pt = P[basA + it * 64 + lane];
            int pi = basA + it * 64 + lane;
#pragma unroll
            for (int qi = 0; qi < QB; ++qi)
                upd2(qdist(ax[qi], ay[qi], az[qi], a2[qi], pt), pi,
                     d1[qi], i1[qi], d2[qi], i2[qi]);
        }
    }
    // butterfly lex-merge across 64 lanes
#pragma unroll
    for (int off = 1; off < 64; off <<= 1) {
#pragma unroll
        for (int qi = 0; qi < QB; ++qi) {
            float od1 = __shfl_xor(d1[qi], off); int oi1 = __shfl_xor(i1[qi], off);
            float od2 = __shfl_xor(d2[qi], off); int oi2 = __shfl_xor(i2[qi], off);
            ins_lex(od1, oi1, d1[qi], i1[qi], d2[qi], i2[qi]);
            ins_lex(od2, oi2, d1[qi], i1[qi], d2[qi], i2[qi]);
        }
    }
    if (lane == 0) {
#pragma unroll
        for (int qi = 0; qi < QB; ++qi)
            wpart[wave][qi] = make_int4(__float_as_int(d1[qi]), i1[qi],
                                        __float_as_int(d2[qi]), i2[qi]);
    }
    __syncthreads();
    if (tid < QB) {
        int4 p0 = wpart[0][tid];
        float b1 = __int_as_float(p0.x), b2 = __int_as_float(p0.z);
        int   j1 = p0.y,                 j2 = p0.w;
#pragma unroll
        for (int w = 1; w < NW; ++w) {
            int4 p = wpart[w][tid];
            ins_lex(__int_as_float(p.x), p.y, b1, j1, b2, j2);
            ins_lex(__int_as_float(p.z), p.w, b1, j1, b2, j2);
        }
        seedm[tid] = make_int4(__float_as_int(b1), j1, __float_as_int(b2), j2);
    }
    __syncthreads();

    // tau_q = seed d2 (upper bound on final d2), forced to SGPR
    float tau[QB];
#pragma unroll
    for (int qi = 0; qi < QB; ++qi)
        tau[qi] = __int_as_float(__builtin_amdgcn_readfirstlane(seedm[qi].z));

    // ---------------- Phase B: filtered scan over [SEED, N) ----------------
#pragma unroll
    for (int qi = 0; qi < QB; ++qi) {
        d1[qi] = __int_as_float(0x7f800000); d2[qi] = d1[qi];
        i1[qi] = 0x7fffffff; i2[qi] = 0x7fffffff;
    }
    {
        int basB = SEED + wave * RESTW;
        const float4* PB = P + basB;
        float4 pt = PB[lane];
        for (int it = 0; it < NITB; ++it) {
            int nx = (it + 1 < NITB) ? it + 1 : NITB - 1;
            float4 ptn = PB[nx * 64 + lane];       // prefetch next point
            int pi = basB + it * 64 + lane;
#pragma unroll
            for (int qi = 0; qi < QB; ++qi) {
                float d = qdist(ax[qi], ay[qi], az[qi], a2[qi], pt);
                if (__ballot(d < tau[qi]))          // wave-uniform, ~6% fire
                    upd2(d, pi, d1[qi], i1[qi], d2[qi], i2[qi]);
            }
            pt = ptn;
        }
    }
    // butterfly lex-merge across lanes
#pragma unroll
    for (int off = 1; off < 64; off <<= 1) {
#pragma unroll
        for (int qi = 0; qi < QB; ++qi) {
            float od1 = __shfl_xor(d1[qi], off); int oi1 = __shfl_xor(i1[qi], off);
            float od2 = __shfl_xor(d2[qi], off); int oi2 = __shfl_xor(i2[qi], off);
            ins_lex(od1, oi1, d1[qi], i1[qi], d2[qi], i2[qi]);
            ins_lex(od2, oi2, d1[qi], i1[qi], d2[qi], i2[qi]);
        }
    }
    if (lane == 0) {
#pragma unroll
        for (int qi = 0; qi < QB; ++qi)
            wpart[wave][qi] = make_int4(__float_as_int(d1[qi]), i1[qi],
                                        __float_as_int(d2[qi]), i2[qi]);
    }
    __syncthreads();

    // final merge: 4 wave partials + seed pair -> second-nearest index
    if (tid < QB) {
        int4 s = seedm[tid];
        float b1 = __int_as_float(s.x), b2 = __int_as_float(s.z);
        int   j1 = s.y,                 j2 = s.w;
#pragma unroll
        for (int w = 0; w < NW; ++w) {
            int4 p = wpart[w][tid];
            ins_lex(__int_as_float(p.x), p.y, b1, j1, b2, j2);
            ins_lex(__int_as_float(p.z), p.w, b1, j1, b2, j2);
        }
        sidx[tid] = j2;
    }
    __syncthreads();

    // fused gather: QB rows of 256 floats; 32 threads per row, 2 float4 each
    int qi = tid >> 5;
    int cj = tid & 31;
    int row = sidx[qi];
    const float4* sp = (const float4*)(feats + (size_t)row * C_F);
    float4* dp = (float4*)(out + ((size_t)side * M_Q + q0 + qi) * (size_t)C_F);
    dp[cj]      = sp[cj];
    dp[cj + 32] = sp[cj + 32];
}

extern "C" void kernel_launch(void* const* d_in, const int* in_sizes, int n_in,
                              void* d_out, int out_size, void* d_ws, size_t ws_size,
                              hipStream_t stream) {
    const float* src  = (const float*)d_in[0];
    const float* tgt  = (const float*)d_in[1];
    const float* c0   = (const float*)d_in[2];  // src_coords   (N,3)
    const float* c1   = (const float*)d_in[3];  // tgt_coords   (N,3)
    const float* sh0  = (const float*)d_in[4];  // src_shortcut (M,3)
    const float* sh1  = (const float*)d_in[5];  // tgt_shortcut (M,3)
    float* out = (float*)d_out;
    float4* pts = (float4*)d_ws;                // 2*N*16B = 1 MB

    hipLaunchKernelGGL(pack_pts, dim3(2 * N_PTS / 256), dim3(256), 0, stream,
                       c0, c1, pts);
    hipLaunchKernelGGL(pool_gather2, dim3(2 * NQB), dim3(256), 0, stream,
                       src, tgt, sh0, sh1, pts, out);
}

// Round 6
// 131.114 us; speedup vs baseline: 3.1432x; 2.0289x over previous
//
#include <hip/hip_runtime.h>

#define N_PTS 32768
#define M_Q   8192
#define C_F   256
#define QB    8                // queries per block
#define NW    4                // waves per block
#define WPTS  (N_PTS / NW)     // 8192 points per wave
#define NCHK  4                // chunks per lane
#define CITER 32               // iterations (points) per lane-chunk
#define NQB   (M_Q / QB)       // 1024 query blocks per side

__device__ __forceinline__ float rn_mul(float a, float b) { return __fmul_rn(a, b); }
__device__ __forceinline__ float rn_add(float a, float b) { return __fadd_rn(a, b); }

// exact-numpy distance: d = round((a2+b2) - 2*dot), dot = sgemm fma chain
__device__ __forceinline__ float qdist(float ax, float ay, float az, float a2,
                                       const float4& p) {
    float dot = __builtin_fmaf(az, p.z, __builtin_fmaf(ay, p.y, rn_mul(ax, p.x)));
    return __builtin_fmaf(-2.0f, dot, rn_add(a2, p.w));
}

// exact lexicographic (d,i) insert into running top-2 pair (order-independent)
__device__ __forceinline__ void ins_lex(float d, int i, float& b1, int& j1,
                                        float& b2, int& j2) {
    bool lt1 = (d < b1) || (d == b1 && i < j1);
    bool lt2 = (d < b2) || (d == b2 && i < j2);
    b2 = lt1 ? b1 : (lt2 ? d : b2);
    j2 = lt1 ? j1 : (lt2 ? i : j2);
    b1 = lt1 ? d : b1;
    j1 = lt1 ? i : j1;
}

// merge two (v1<=v2) value-pairs -> two smallest values overall
__device__ __forceinline__ void vpair_merge(float& a1, float& a2, float b1, float b2) {
    float n1 = fminf(a1, b1);
    float n2 = fminf(fmaxf(a1, b1), fminf(a2, b2));
    a1 = n1; a2 = n2;
}

// Pack [x,y,z,b2] per point for both sides into workspace.
__global__ __launch_bounds__(256) void pack_pts(const float* __restrict__ c0,
                                                const float* __restrict__ c1,
                                                float4* __restrict__ pts) {
    int t = blockIdx.x * blockDim.x + threadIdx.x;   // 0 .. 2N-1
    int side = t >> 15;
    int n = t & (N_PTS - 1);
    const float* c = side ? c1 : c0;
    float x = c[n * 3 + 0], y = c[n * 3 + 1], z = c[n * 3 + 2];
    float b2 = rn_add(rn_add(rn_mul(x, x), rn_mul(y, y)), rn_mul(z, z));
    pts[t] = make_float4(x, y, z, b2);
}

__global__ __launch_bounds__(256, 4) void pool_chunked(
    const float* __restrict__ src, const float* __restrict__ tgt,
    const float* __restrict__ sc0, const float* __restrict__ sc1,
    const float4* __restrict__ pts, float* __restrict__ out)
{
    __shared__ float wb1[NW][QB], wb2[NW][QB];   // per-wave 2-smallest chunk-minima
    __shared__ int4  wpart[NW][QB];              // per-wave lex top-2 partials
    __shared__ int   sidx[QB];

    int bid  = blockIdx.x;           // 2 * NQB = 2048
    int side = bid >> 10;
    int qb   = bid & 1023;
    const float* feats = side ? tgt : src;
    const float* sc    = side ? sc1 : sc0;

    int tid  = threadIdx.x;
    int wave = tid >> 6;
    int lane = tid & 63;
    int q0   = qb * QB;
    int wbase = wave * WPTS;
    const float4* P = pts + (size_t)side * N_PTS + wbase;

    float ax[QB], ay[QB], az[QB], a2[QB];
#pragma unroll
    for (int q = 0; q < QB; ++q) {
        int qq = q0 + q;
        float x = sc[qq * 3 + 0], y = sc[qq * 3 + 1], z = sc[qq * 3 + 2];
        ax[q] = x; ay[q] = y; az[q] = z;
        a2[q] = rn_add(rn_add(rn_mul(x, x), rn_mul(y, y)), rn_mul(z, z));
    }

    // ---------------- Pass 1: per-lane chunk minima (branchless) ----------------
    float m[NCHK][QB];
#pragma unroll
    for (int c = 0; c < NCHK; ++c)
#pragma unroll
        for (int q = 0; q < QB; ++q) m[c][q] = __int_as_float(0x7f800000);

#pragma unroll
    for (int c = 0; c < NCHK; ++c) {
#pragma unroll 8
        for (int j = 0; j < CITER; ++j) {
            float4 pt = P[(c * CITER + j) * 64 + lane];
#pragma unroll
            for (int q = 0; q < QB; ++q) {
                float d = qdist(ax[q], ay[q], az[q], a2[q], pt);
                m[c][q] = fminf(m[c][q], d);
            }
        }
    }

    // ---------------- beta: 2nd-smallest chunk-min over the whole block ----------
    float p1[QB], p2[QB];
#pragma unroll
    for (int q = 0; q < QB; ++q) {
        float s1 = fminf(m[0][q], m[1][q]), t1 = fmaxf(m[0][q], m[1][q]);
        float s2 = fminf(m[2][q], m[3][q]), t2 = fmaxf(m[2][q], m[3][q]);
        p1[q] = fminf(s1, s2);
        p2[q] = fminf(fmaxf(s1, s2), fminf(t1, t2));
    }
#pragma unroll
    for (int off = 1; off < 64; off <<= 1) {
#pragma unroll
        for (int q = 0; q < QB; ++q) {
            float o1 = __shfl_xor(p1[q], off);
            float o2 = __shfl_xor(p2[q], off);
            vpair_merge(p1[q], p2[q], o1, o2);
        }
    }
    if (lane == 0) {
#pragma unroll
        for (int q = 0; q < QB; ++q) { wb1[wave][q] = p1[q]; wb2[wave][q] = p2[q]; }
    }
    __syncthreads();

    float beta[QB];
#pragma unroll
    for (int q = 0; q < QB; ++q) {
        float b1 = wb1[0][q], b2 = wb2[0][q];
#pragma unroll
        for (int w = 1; w < NW; ++w) vpair_merge(b1, b2, wb1[w][q], wb2[w][q]);
        beta[q] = b2;   // upper bound on the query's global 2nd-smallest distance
    }

    // ---------------- Pass 2: rescan surviving chunks exactly (lex) -------------
    float d1[QB], d2[QB];
    int   i1[QB], i2[QB];
#pragma unroll
    for (int q = 0; q < QB; ++q) {
        d1[q] = __int_as_float(0x7f800000); d2[q] = d1[q];
        i1[q] = 0x7fffffff; i2[q] = 0x7fffffff;
    }

#pragma unroll
    for (int c = 0; c < NCHK; ++c) {
#pragma unroll
        for (int q = 0; q < QB; ++q) {
            unsigned long long mask = __ballot(m[c][q] <= beta[q]);
            while (mask) {
                int l = (int)__builtin_ctzll(mask);
                mask &= mask - 1;
                if (lane < CITER) {
                    int off = (c * CITER + lane) * 64 + l;   // j = lane
                    float4 pt = P[off];
                    int pi = wbase + off;
                    float d = qdist(ax[q], ay[q], az[q], a2[q], pt);
                    ins_lex(d, pi, d1[q], i1[q], d2[q], i2[q]);
                }
            }
        }
    }

    // butterfly lex-merge across 64 lanes
#pragma unroll
    for (int off = 1; off < 64; off <<= 1) {
#pragma unroll
        for (int q = 0; q < QB; ++q) {
            float od1 = __shfl_xor(d1[q], off); int oi1 = __shfl_xor(i1[q], off);
            float od2 = __shfl_xor(d2[q], off); int oi2 = __shfl_xor(i2[q], off);
            ins_lex(od1, oi1, d1[q], i1[q], d2[q], i2[q]);
            ins_lex(od2, oi2, d1[q], i1[q], d2[q], i2[q]);
        }
    }
    if (lane == 0) {
#pragma unroll
        for (int q = 0; q < QB; ++q)
            wpart[wave][q] = make_int4(__float_as_int(d1[q]), i1[q],
                                       __float_as_int(d2[q]), i2[q]);
    }
    __syncthreads();

    // final merge across waves -> second-nearest index
    if (tid < QB) {
        int4 p0 = wpart[0][tid];
        float b1 = __int_as_float(p0.x), b2 = __int_as_float(p0.z);
        int   j1 = p0.y,                 j2 = p0.w;
#pragma unroll
        for (int w = 1; w < NW; ++w) {
            int4 p = wpart[w][tid];
            ins_lex(__int_as_float(p.x), p.y, b1, j1, b2, j2);
            ins_lex(__int_as_float(p.z), p.w, b1, j1, b2, j2);
        }
        sidx[tid] = j2;
    }
    __syncthreads();

    // fused gather: QB rows of 256 floats; 32 threads per row, 2 float4 each
    int qi = tid >> 5;
    int cj = tid & 31;
    int row = sidx[qi];
    const float4* sp = (const float4*)(feats + (size_t)row * C_F);
    float4* dp = (float4*)(out + ((size_t)side * M_Q + q0 + qi) * (size_t)C_F);
    dp[cj]      = sp[cj];
    dp[cj + 32] = sp[cj + 32];
}

extern "C" void kernel_launch(void* const* d_in, const int* in_sizes, int n_in,
                              void* d_out, int out_size, void* d_ws, size_t ws_size,
                              hipStream_t stream) {
    const float* src  = (const float*)d_in[0];
    const float* tgt  = (const float*)d_in[1];
    const float* c0   = (const float*)d_in[2];  // src_coords   (N,3)
    const float* c1   = (const float*)d_in[3];  // tgt_coords   (N,3)
    const float* sh0  = (const float*)d_in[4];  // src_shortcut (M,3)
    const float* sh1  = (const float*)d_in[5];  // tgt_shortcut (M,3)
    float* out = (float*)d_out;
    float4* pts = (float4*)d_ws;                // 2*N*16B = 1 MB

    hipLaunchKernelGGL(pack_pts, dim3(2 * N_PTS / 256), dim3(256), 0, stream,
                       c0, c1, pts);
    hipLaunchKernelGGL(pool_chunked, dim3(2 * NQB), dim3(256), 0, stream,
                       src, tgt, sh0, sh1, pts, out);
}

// Round 7
// 97.881 us; speedup vs baseline: 4.2103x; 1.3395x over previous
//
#include <hip/hip_runtime.h>

#define N_PTS 32768
#define M_Q   8192
#define C_F   256
#define QW    8                  // queries per wave
#define NW    4                  // waves per block
#define QBL   (QW * NW)          // 32 queries per block
#define NSL   8                  // chunk slots per lane (chunk = 64 points)
#define CHPTS 1024               // points per staged LDS chunk
#define NCH   (N_PTS / CHPTS)    // 32 chunks
#define MU    5e-4f              // rigorous e-vs-d* margin (>= 2*1.03e-4)

__device__ __forceinline__ float rn_mul(float a, float b) { return __fmul_rn(a, b); }
__device__ __forceinline__ float rn_add(float a, float b) { return __fadd_rn(a, b); }
__device__ __forceinline__ float rfl(float x) {
    return __int_as_float(__builtin_amdgcn_readfirstlane(__float_as_int(x)));
}

// exact lexicographic (d,i) insert into running top-2 pair
__device__ __forceinline__ void ins_lex(float d, int i, float& b1, int& j1,
                                        float& b2, int& j2) {
    bool lt1 = (d < b1) || (d == b1 && i < j1);
    bool lt2 = (d < b2) || (d == b2 && i < j2);
    b2 = lt1 ? b1 : (lt2 ? d : b2);
    j2 = lt1 ? j1 : (lt2 ? i : j2);
    b1 = lt1 ? d : b1;
    j1 = lt1 ? i : j1;
}

// merge two value-pairs (each a1<=a2) -> two smallest overall
__device__ __forceinline__ void vpair_merge(float& a1, float& a2, float b1, float b2) {
    float n1 = fminf(a1, b1);
    float n2 = fminf(fmaxf(a1, b1), fminf(a2, b2));
    a1 = n1; a2 = n2;
}

// Pack [x,y,z,b2] per point for both sides into workspace.
__global__ __launch_bounds__(256) void pack_pts(const float* __restrict__ c0,
                                                const float* __restrict__ c1,
                                                float4* __restrict__ pts) {
    int t = blockIdx.x * blockDim.x + threadIdx.x;   // 0 .. 2N-1
    int side = t >> 15;
    int n = t & (N_PTS - 1);
    const float* c = side ? c1 : c0;
    float x = c[n * 3 + 0], y = c[n * 3 + 1], z = c[n * 3 + 2];
    // numpy: sum(b*b,-1) = (x*x + y*y) + z*z, plain rounded ops
    float b2 = rn_add(rn_add(rn_mul(x, x), rn_mul(y, y)), rn_mul(z, z));
    pts[t] = make_float4(x, y, z, b2);
}

__global__ __launch_bounds__(256) void pool_lds(
    const float* __restrict__ src, const float* __restrict__ tgt,
    const float* __restrict__ sc0, const float* __restrict__ sc1,
    const float4* __restrict__ pts, float* __restrict__ out)
{
    __shared__ float4 sbuf[2][CHPTS];   // 32 KB double buffer
    __shared__ int sidx[QBL];

    int bid  = blockIdx.x;              // 512 blocks
    int side = bid >> 8;
    int qblk = bid & 255;
    const float* feats = side ? tgt : src;
    const float* sc    = side ? sc1 : sc0;
    const float4* Pg   = pts + (size_t)side * N_PTS;

    int tid  = threadIdx.x;
    int wave = tid >> 6;
    int lane = tid & 63;
    int q0   = qblk * QBL;

    // per-wave query scalars -> SGPR via readfirstlane (wave-uniform)
    float ax[QW], ay[QW], az[QW], a2[QW];
#pragma unroll
    for (int q = 0; q < QW; ++q) {
        int qq = q0 + wave * QW + q;
        float x = rfl(sc[qq * 3 + 0]);
        float y = rfl(sc[qq * 3 + 1]);
        float z = rfl(sc[qq * 3 + 2]);
        ax[q] = x; ay[q] = y; az[q] = z;
        a2[q] = rn_add(rn_add(rn_mul(x, x), rn_mul(y, y)), rn_mul(z, z));
    }

    float m[NSL][QW];
#pragma unroll
    for (int s = 0; s < NSL; ++s)
#pragma unroll
        for (int q = 0; q < QW; ++q) m[s][q] = __int_as_float(0x7f800000);

    // stage chunk 0
#pragma unroll
    for (int k = 0; k < 4; ++k)
        sbuf[0][k * 256 + tid] = Pg[k * 256 + tid];
    __syncthreads();

    // -------- Pass 1: convoy scan, per-lane chunk minima in e-space --------
#pragma unroll
    for (int s = 0; s < NSL; ++s) {
        for (int cc = 0; cc < 4; ++cc) {
            int ch = s * 4 + cc;
            float4 st0, st1, st2, st3;
            bool hs = (ch + 1 < NCH);
            if (hs) {                      // issue next-chunk loads early
                const float4* gp = Pg + (ch + 1) * CHPTS;
                st0 = gp[0 * 256 + tid]; st1 = gp[1 * 256 + tid];
                st2 = gp[2 * 256 + tid]; st3 = gp[3 * 256 + tid];
            }
            const float4* cb = sbuf[ch & 1];
#pragma unroll 4
            for (int j = 0; j < 16; ++j) {
                float4 pt = cb[j * 64 + lane];
#pragma unroll
                for (int q = 0; q < QW; ++q) {
                    float dot = __builtin_fmaf(az[q], pt.z,
                                 __builtin_fmaf(ay[q], pt.y, rn_mul(ax[q], pt.x)));
                    float e = __builtin_fmaf(-2.0f, dot, pt.w);  // b2 - 2*dot
                    m[s][q] = fminf(m[s][q], e);
                }
            }
            if (hs) {                      // write-late into the other buffer
                float4* nb = sbuf[(ch + 1) & 1];
                nb[0 * 256 + tid] = st0; nb[1 * 256 + tid] = st1;
                nb[2 * 256 + tid] = st2; nb[3 * 256 + tid] = st3;
            }
            __syncthreads();
        }
    }

    // -------- beta per query: 2nd-smallest chunk-min over 512 chunks --------
    float beta[QW];
#pragma unroll
    for (int q = 0; q < QW; ++q) {
        float l0 = fminf(m[0][q], m[1][q]), h0 = fmaxf(m[0][q], m[1][q]);
        float l1 = fminf(m[2][q], m[3][q]), h1 = fmaxf(m[2][q], m[3][q]);
        float l2 = fminf(m[4][q], m[5][q]), h2 = fmaxf(m[4][q], m[5][q]);
        float l3 = fminf(m[6][q], m[7][q]), h3 = fmaxf(m[6][q], m[7][q]);
        float p1a = fminf(l0, l1), p2a = fminf(fmaxf(l0, l1), fminf(h0, h1));
        float p1b = fminf(l2, l3), p2b = fminf(fmaxf(l2, l3), fminf(h2, h3));
        float p1 = fminf(p1a, p1b);
        float p2 = fminf(fmaxf(p1a, p1b), fminf(p2a, p2b));
#pragma unroll
        for (int off = 1; off < 64; off <<= 1) {
            float o1 = __shfl_xor(p1, off);
            float o2 = __shfl_xor(p2, off);
            vpair_merge(p1, p2, o1, o2);
        }
        beta[q] = p2 + MU;
    }

    // -------- Pass 2: exact rescan of surviving chunks (lex, d*-space) -----
    float D1[QW], D2[QW];
    int   I1[QW], I2[QW];
#pragma unroll
    for (int q = 0; q < QW; ++q) {
        D1[q] = __int_as_float(0x7f800000); D2[q] = D1[q];
        I1[q] = 0x7fffffff; I2[q] = 0x7fffffff;
    }
#pragma unroll
    for (int s = 0; s < NSL; ++s) {
#pragma unroll
        for (int q = 0; q < QW; ++q) {
            unsigned long long fm = __ballot(m[s][q] <= beta[q]);
            while (fm) {                        // ~2-3 fires per query
                int l = (int)__builtin_ctzll(fm);
                fm &= fm - 1;
                int pidx = s * 4096 + lane * 64 + l;   // lane j rescans pt j of chunk
                float4 pt = Pg[pidx];
                float dot = __builtin_fmaf(az[q], pt.z,
                             __builtin_fmaf(ay[q], pt.y, rn_mul(ax[q], pt.x)));
                float dd = __builtin_fmaf(-2.0f, dot, rn_add(a2[q], pt.w));
                ins_lex(dd, pidx, D1[q], I1[q], D2[q], I2[q]);
            }
        }
    }

    // butterfly lex-merge across 64 lanes
#pragma unroll
    for (int off = 1; off < 64; off <<= 1) {
#pragma unroll
        for (int q = 0; q < QW; ++q) {
            float od1 = __shfl_xor(D1[q], off); int oi1 = __shfl_xor(I1[q], off);
            float od2 = __shfl_xor(D2[q], off); int oi2 = __shfl_xor(I2[q], off);
            ins_lex(od1, oi1, D1[q], I1[q], D2[q], I2[q]);
            ins_lex(od2, oi2, D1[q], I1[q], D2[q], I2[q]);
        }
    }
    if (lane == 0) {
#pragma unroll
        for (int q = 0; q < QW; ++q) sidx[wave * QW + q] = I2[q];
    }
    __syncthreads();

    // -------- fused gather: 32 rows of 1 KB, fully coalesced ---------------
#pragma unroll
    for (int rg = 0; rg < 4; ++rg) {
        int r = rg * 8 + (tid >> 5);
        int c32 = tid & 31;
        int row = sidx[r];
        const float4* sp = (const float4*)(feats + (size_t)row * C_F);
        float4* dp = (float4*)(out + ((size_t)side * M_Q + q0 + r) * (size_t)C_F);
        dp[c32]      = sp[c32];
        dp[c32 + 32] = sp[c32 + 32];
    }
}

extern "C" void kernel_launch(void* const* d_in, const int* in_sizes, int n_in,
                              void* d_out, int out_size, void* d_ws, size_t ws_size,
                              hipStream_t stream) {
    const float* src  = (const float*)d_in[0];
    const float* tgt  = (const float*)d_in[1];
    const float* c0   = (const float*)d_in[2];  // src_coords   (N,3)
    const float* c1   = (const float*)d_in[3];  // tgt_coords   (N,3)
    const float* sh0  = (const float*)d_in[4];  // src_shortcut (M,3)
    const float* sh1  = (const float*)d_in[5];  // tgt_shortcut (M,3)
    float* out = (float*)d_out;
    float4* pts = (float4*)d_ws;                // 2*N*16B = 1 MB

    hipLaunchKernelGGL(pack_pts, dim3(2 * N_PTS / 256), dim3(256), 0, stream,
                       c0, c1, pts);
    hipLaunchKernelGGL(pool_lds, dim3(2 * (M_Q / QBL)), dim3(256), 0, stream,
                       src, tgt, sh0, sh1, pts, out);
}